// Round 8
// baseline (111.742 us; speedup 1.0000x reference)
//
#include <hip/hip_runtime.h>
#include <math.h>

// N_PTS=1e6, K_DIM=3, N_BINS=21; wv row = 43 floats (v_tilde[22] | w_tilde[21])
#define NROWS   3000000
#define RPC     60                    // rows per chunk = 20 points; 10320 B, 16B-aligned
#define NCHUNKS (NROWS / RPC)         // 50000 exact
#define BPCU    7                     // LDS-bound: 2*10320 B = 20640 B/block
#define GRID    (256 * BPCU)          // 1792 persistent 1-wave blocks
#define NBINS   21
#define NV      22
#define DROW    43
#define FPC     (RPC * DROW)          // 2580 floats
#define F4PC    (FPC / 4)             // 645 = 10*64 + 5

#define AS1 __attribute__((address_space(1)))
#define AS3 __attribute__((address_space(3)))

__device__ __forceinline__ void gload16(const void* g, void* l) {
    __builtin_amdgcn_global_load_lds((const AS1 void*)g, (AS3 void*)l, 16, 0, 0);
}

// Exactly 11 vmem load instrs; LDS dst strictly linear (uniform base + lane*16).
__device__ __forceinline__ void prefetch(const float4* __restrict__ wv4,
                                         int c, float* buf, int tid)
{
    const float4* s = wv4 + (size_t)c * F4PC;
    float4* d = reinterpret_cast<float4*>(buf);
#pragma unroll
    for (int it = 0; it < 10; ++it)                  // 10*64 = 640
        gload16(s + it * 64 + tid, d + it * 64 + tid);
    if (tid < (F4PC - 640))                          // 5 tail (lanes 0-4, always issues)
        gload16(s + 640 + tid, d + 640 + tid);
}

__global__ __launch_bounds__(64) void pwquad_kernel(
    const float* __restrict__ y,
    const float* __restrict__ wv,
    float* __restrict__ out)
{
    __shared__ float buf[2][FPC];     // 20640 B double buffer

    const int tid = threadIdx.x;
    const float4* wv4 = reinterpret_cast<const float4*>(wv);
    const float EPSF = 1.1920929e-07f;   // np.finfo(float32).eps

    // Prologue: fill buffer 0, full drain once (no stores outstanding yet).
    prefetch(wv4, blockIdx.x, buf[0], tid);
    asm volatile("s_waitcnt vmcnt(0)" ::: "memory");

    int cur = 0;
    for (int c = blockIdx.x; c < NCHUNKS; c += GRID) {
        const int cn = c + GRID;
        // Issue next chunk's DMA FIRST; it stays in flight across this whole
        // iteration (loads are the OLDEST vmem ops of this iteration).
        if (cn < NCHUNKS)
            prefetch(wv4, cn, buf[cur ^ 1], tid);

        float ltv = 0.f;
        if (tid < RPC) {
            const float yv = y[(size_t)c * RPC + tid];       // coalesced direct load
            const float* myrow = &buf[cur][tid * DROW];      // 2-way bank alias (free)

            // w = exp(w_tilde); normalize
            float w[NBINS];
            float wnorm = 0.f;
#pragma unroll
            for (int j = 0; j < NBINS; ++j) { w[j] = __expf(myrow[NV + j]); wnorm += w[j]; }
            const float invw = 1.0f / wnorm;
#pragma unroll
            for (int j = 0; j < NBINS; ++j) w[j] *= invw;

            // ve = exp(v_tilde); trapezoid normalization
            float v[NV];
#pragma unroll
            for (int i = 0; i < NV; ++i) v[i] = __expf(myrow[i]);
            float T = 0.f;
#pragma unroll
            for (int j = 0; j < NBINS; ++j) T += (v[j] + v[j + 1]) * 0.5f * w[j];
            const float invT = 1.0f / T;
#pragma unroll
            for (int i = 0; i < NV; ++i) v[i] = fmaxf(v[i] * invT, 1e-6f);

            // Edge search: latch last k with vw_k <= y (vw non-decreasing)
            float vw = 0.f, wsum = 0.f;
            float vwe = 0.f, wse = 0.f;
            float v0 = v[0], v1 = v[1], we = w[0];
#pragma unroll
            for (int j = 0; j < 20; ++j) {
                const float inc = (v[j] + v[j + 1]) * 0.5f * w[j];
                vw += inc;
                wsum += w[j];
                const bool q = (vw <= yv);
                vwe = q ? vw       : vwe;
                wse = q ? wsum     : wse;
                v0  = q ? v[j + 1] : v0;
                v1  = q ? v[j + 2] : v1;
                we  = q ? w[j + 1] : we;
            }

            // Quadratic solve
            float a = (v1 - v0) * we;
            const float bq = v0 * we;
            const float cc = vwe - yv;
            a = (fabsf(a) < EPSF) ? EPSF : a;
            const float dd = fmaxf(bq * bq - 2.0f * a * cc, 0.f);
            const float sq = sqrtf(dd);
            const float sol1 = (-bq - sq) / a;
            const float sol2 = (-bq + sq) / a;
            float sol = (sol1 >= 0.f && sol1 < 1.f) ? sol1 : sol2;
            sol = fminf(fmaxf(sol, EPSF), 1.f - EPSF);
            float x = we * sol + wse;
            x = fminf(fmaxf(x, EPSF), 1.f - EPSF);

            out[(size_t)c * RPC + tid] = x;                  // store #1
            ltv = __logf(v0 + (v1 - v0) * sol);
        }

        // logj via intra-wave shuffle (60 rows = 20 whole points within the wave)
        const float t1 = __shfl(ltv, (tid + 1) & 63);
        const float t2 = __shfl(ltv, (tid + 2) & 63);
        if (tid < RPC && (tid % 3) == 0) {
            out[NROWS + (size_t)c * (RPC / 3) + tid / 3] = -(ltv + t1 + t2);  // store #2
        }

        // Counted wait: the 11 prefetch loads are the oldest outstanding vmem;
        // only the 2 stores above are younger. outstanding<=2  <=>  loads done.
        // NEVER vmcnt(0) here (would wall on store acks - the R4 mistake).
        if (cn < NCHUNKS)
            asm volatile("s_waitcnt vmcnt(2)" ::: "memory");

        cur ^= 1;
    }
}

extern "C" void kernel_launch(void* const* d_in, const int* in_sizes, int n_in,
                              void* d_out, int out_size, void* d_ws, size_t ws_size,
                              hipStream_t stream) {
    const float* y  = (const float*)d_in[0];
    const float* wv = (const float*)d_in[1];
    float* out = (float*)d_out;

    pwquad_kernel<<<GRID, 64, 0, stream>>>(y, wv, out);
}

// Round 9
// 103.707 us; speedup vs baseline: 1.0775x; 1.0775x over previous
//
#include <hip/hip_runtime.h>
#include <math.h>

// N_PTS=1e6, K_DIM=3, N_BINS=21; wv row = 43 floats (v_tilde[22] | w_tilde[21])
#define NROWS        3000000
#define NTHREADS     128                 // 2 waves
#define ROWS_PER_BLK 120                 // 40 points; 120*43*4 = 20640 B (16B-aligned)
#define RPWAVE       60                  // rows computed per wave (20 whole points)
#define NBINS        21
#define NV           22
#define DROW         43
#define F_PER_BLK    (ROWS_PER_BLK * DROW)   // 5160 floats
#define F4_PER_BLK   (F_PER_BLK / 4)         // 1290 = 10*128 + 10
#define NBLOCKS      (NROWS / ROWS_PER_BLK)  // 25000 exact

__global__ __launch_bounds__(NTHREADS) void pwquad_kernel(
    const float* __restrict__ y,
    const float* __restrict__ wv,
    float* __restrict__ out)
{
    __shared__ float buf[F_PER_BLK];      // 20640 B
    __shared__ float yb[ROWS_PER_BLK];    // 480 B

    const int tid = threadIdx.x;
    const int b   = blockIdx.x;
    const float EPSF = 1.1920929e-07f;    // np.finfo(float32).eps

    // ---- Stage 120 rows + y into LDS: plain coalesced dwordx4 -> regs -> LDS
    // (the R1 path: highest measured fetch rate of all variants)
    {
        const float4* s = reinterpret_cast<const float4*>(wv) + (size_t)b * F4_PER_BLK;
        float4* d = reinterpret_cast<float4*>(buf);
        float4 r[10], rt, ry;
#pragma unroll
        for (int it = 0; it < 10; ++it) r[it] = s[it * NTHREADS + tid];   // 1280
        const bool tail = (tid < (F4_PER_BLK - 10 * NTHREADS));           // 10
        if (tail) rt = s[10 * NTHREADS + tid];
        const bool yl = (tid < (ROWS_PER_BLK / 4));                       // 30
        if (yl) ry = reinterpret_cast<const float4*>(y)[(size_t)b * (ROWS_PER_BLK / 4) + tid];
#pragma unroll
        for (int it = 0; it < 10; ++it) d[it * NTHREADS + tid] = r[it];
        if (tail) d[10 * NTHREADS + tid] = rt;
        if (yl) reinterpret_cast<float4*>(yb)[tid] = ry;
    }
    __syncthreads();

    // ---- Compute: wave w, lane l<60 owns row w*60+l (20 whole points per wave)
    const int wave = tid >> 6, lane = tid & 63;
    const int rrow = wave * RPWAVE + lane;
    float ltv = 0.f;

    if (lane < RPWAVE) {
        const float yv = yb[rrow];
        const float* myrow = &buf[rrow * DROW];   // stride 43 -> 2-way alias (free)

        // w = exp(w_tilde); normalize
        float w[NBINS];
        float wnorm = 0.f;
#pragma unroll
        for (int j = 0; j < NBINS; ++j) { w[j] = __expf(myrow[NV + j]); wnorm += w[j]; }
        const float invw = 1.0f / wnorm;
#pragma unroll
        for (int j = 0; j < NBINS; ++j) w[j] *= invw;

        // ve = exp(v_tilde); trapezoid normalization
        float v[NV];
#pragma unroll
        for (int i = 0; i < NV; ++i) v[i] = __expf(myrow[i]);
        float T = 0.f;
#pragma unroll
        for (int j = 0; j < NBINS; ++j) T += (v[j] + v[j + 1]) * 0.5f * w[j];
        const float invT = 1.0f / T;
#pragma unroll
        for (int i = 0; i < NV; ++i) v[i] = fmaxf(v[i] * invT, 1e-6f);

        // Edge search: latch last k with vw_k <= y (vw non-decreasing)
        float vw = 0.f, wsum = 0.f;
        float vwe = 0.f, wse = 0.f;
        float v0 = v[0], v1 = v[1], we = w[0];
#pragma unroll
        for (int j = 0; j < 20; ++j) {
            const float inc = (v[j] + v[j + 1]) * 0.5f * w[j];
            vw += inc;
            wsum += w[j];
            const bool q = (vw <= yv);
            vwe = q ? vw       : vwe;
            wse = q ? wsum     : wse;
            v0  = q ? v[j + 1] : v0;
            v1  = q ? v[j + 2] : v1;
            we  = q ? w[j + 1] : we;
        }

        // Quadratic solve
        float a = (v1 - v0) * we;
        const float bq = v0 * we;
        const float cc = vwe - yv;
        a = (fabsf(a) < EPSF) ? EPSF : a;
        const float dd = fmaxf(bq * bq - 2.0f * a * cc, 0.f);
        const float sq = sqrtf(dd);
        const float sol1 = (-bq - sq) / a;
        const float sol2 = (-bq + sq) / a;
        float sol = (sol1 >= 0.f && sol1 < 1.f) ? sol1 : sol2;
        sol = fminf(fmaxf(sol, EPSF), 1.f - EPSF);
        float x = we * sol + wse;
        x = fminf(fmaxf(x, EPSF), 1.f - EPSF);

        out[(size_t)b * ROWS_PER_BLK + rrow] = x;
        ltv = __logf(v0 + (v1 - v0) * sol);
    }

    // logj: intra-wave shuffle over 3 consecutive lanes (rows of one point).
    // No second barrier needed - exchange is within the wave.
    const float t1 = __shfl(ltv, (lane + 1) & 63);
    const float t2 = __shfl(ltv, (lane + 2) & 63);
    if (lane < RPWAVE && (lane % 3) == 0) {
        out[NROWS + (size_t)b * (ROWS_PER_BLK / 3) + (rrow / 3)] = -(ltv + t1 + t2);
    }
}

extern "C" void kernel_launch(void* const* d_in, const int* in_sizes, int n_in,
                              void* d_out, int out_size, void* d_ws, size_t ws_size,
                              hipStream_t stream) {
    const float* y  = (const float*)d_in[0];
    const float* wv = (const float*)d_in[1];
    float* out = (float*)d_out;

    pwquad_kernel<<<NBLOCKS, NTHREADS, 0, stream>>>(y, wv, out);
}